// Round 20
// baseline (106.989 us; speedup 1.0000x reference)
//
#include <hip/hip_runtime.h>

typedef unsigned short u16;
typedef unsigned int u32;
typedef short bf16x8 __attribute__((ext_vector_type(8)));
typedef float f32x4 __attribute__((ext_vector_type(4)));
typedef float f32x8v __attribute__((ext_vector_type(8)));
typedef float f32x16 __attribute__((ext_vector_type(16)));

#define LOG2E 1.44269504f

__device__ __forceinline__ u16 f2b(float f) {
  union { float f; unsigned u; } v; v.f = f;
  unsigned r = v.u + 0x7FFFu + ((v.u >> 16) & 1u);
  return (u16)(r >> 16);
}

__device__ __forceinline__ u32 cvtpk(float a, float b) {
  u32 r;
  asm("v_cvt_pk_bf16_f32 %0, %1, %2" : "=v"(r) : "v"(a), "v"(b));
  return r;
}

__device__ __forceinline__ float max3f(float a, float b, float c) {
  float r;
  asm("v_max3_f32 %0, %1, %2, %3" : "=v"(r) : "v"(a), "v"(b), "v"(c));
  return r;
}

__device__ __forceinline__ void plswap(u32& x, u32& y) {
#if __has_builtin(__builtin_amdgcn_permlane32_swap)
  typedef int v2i __attribute__((ext_vector_type(2)));
  v2i r = __builtin_amdgcn_permlane32_swap((int)x, (int)y, false, false);
  x = (u32)r[0]; y = (u32)r[1];
#else
  u32 sx = (u32)__shfl_xor((int)x, 32, 64);
  u32 sy = (u32)__shfl_xor((int)y, 32, 64);
  bool hi = (threadIdx.x & 63) >= 32;
  u32 nx = hi ? sy : x;
  u32 ny = hi ? y : sx;
  x = nx; y = ny;
#endif
}

// async global->LDS, 16B per lane; LDS dest is wave-uniform base (HW adds lane*16)
__device__ __forceinline__ void gld16(const void* g, void* l) {
  __builtin_amdgcn_global_load_lds((const __attribute__((address_space(1))) void*)g,
                                   (__attribute__((address_space(3))) void*)l, 16, 0, 0);
}

// inverse of LDS fragment swizzle ba(r,o) = (r*64 + o*16) ^ ((r&7)<<4), L = c*16
__device__ __forceinline__ void invswz(int c, int& r, int& o) {
  int rhalf = c >> 3;
  int r2 = (rhalf >> 1) & 1;
  int r0 = ((c >> 2) & 1) ^ r2;
  r = rhalf * 2 + r0;
  int o0 = (c & 1) ^ r0;
  int o1 = ((c >> 1) & 1) ^ (rhalf & 1);
  o = o0 + 2 * o1;
}

// ------------- prep0: cast x (blk<4096) | transpose w_qkv (<6144) | transpose w_out -------------
__global__ __launch_bounds__(256) void k_prep0(const float* __restrict__ x, u16* __restrict__ Xb,
                                               const float* __restrict__ w_qkv, u16* __restrict__ Wqt,
                                               const float* __restrict__ w_out, u16* __restrict__ Wot) {
  __shared__ float tile[32][33];
  int blk = blockIdx.x;
  int tid = threadIdx.x;
  if (blk < 4096) {
    int i = blk * 256 + tid;
    float4 v = ((const float4*)x)[i];
    ushort4 o;
    o.x = f2b(v.x); o.y = f2b(v.y); o.z = f2b(v.z); o.w = f2b(v.w);
    ((ushort4*)Xb)[i] = o;
    return;
  }
  const float* in; u16* out; int R, C, t;
  if (blk < 6144) { t = blk - 4096; in = w_qkv; out = Wqt; R = 1024; C = 2048; }
  else            { t = blk - 6144; in = w_out; out = Wot; R = 1024; C = 1024; }
  int nbx = C >> 5;
  int c0 = (t % nbx) * 32, r0 = (t / nbx) * 32;
  int tx = tid & 31, ty = tid >> 5;
#pragma unroll
  for (int i = 0; i < 32; i += 8)
    tile[ty + i][tx] = in[(size_t)(r0 + ty + i) * C + c0 + tx];
  __syncthreads();
#pragma unroll
  for (int i = 0; i < 32; i += 8)
    out[(size_t)(c0 + ty + i) * R + r0 + tx] = f2b(tile[tx][ty + i]);
}

// ------------- GEMM: BMx128 tile, BK=64 per barrier step (2 swizzled BK=32 halves),
// global_load_lds staging (pre-swizzled source), dbuf, counted vmcnt.
// EPI 0: C fp32 store. EPI 1 (qkv): cols<1536 -> in-register RoPE -> Qb/Kb bf16;
//                                   cols>=1536 -> LDS transpose -> Vt[b*8+kh][d][t] bf16.
template<int BM, int Nsz, int Ksz, int EPI>
__global__ __launch_bounds__(256) void k_gemm(const u16* __restrict__ A, const u16* __restrict__ Bt,
                                              float* __restrict__ C, const float* __restrict__ cs,
                                              const float* __restrict__ sn, u16* __restrict__ Qb,
                                              u16* __restrict__ Kb, u16* __restrict__ Vt) {
  constexpr int MT = BM / 32;       // acc m-tiles per wave
  constexpr int CA = BM / 64;       // A staging calls per K-half
  constexpr int ABy = BM * 128;     // A bytes per buf (BK=64)
  __shared__ u16 sm[BM * 128 + 16384];  // A 2buf + B 2buf; EPI1 epilogue reuse needs 16640 < 32768
  const int tid = threadIdx.x;
  const int l = tid & 63, w = tid >> 6;
  const int wm = w >> 1, wn = w & 1;
  const int m0 = blockIdx.x * BM, n0 = blockIdx.y * 128;
  const int rg = l >> 4, cl = l & 15;
  const int Bbase = BM * 256;       // byte offset of B region

  // staging sources: lane's linear LDS slot c -> (row,off) via inverse swizzle (per K-half)
  const u16* aSrc[2];
  const u16* bSrc[2];
#pragma unroll
  for (int i = 0; i < CA; i++) {
    int r, o; invswz(i * 256 + tid, r, o);
    aSrc[i] = A + (size_t)(m0 + r) * Ksz + o * 8;
  }
#pragma unroll
  for (int i = 0; i < 2; i++) {
    int r, o; invswz(i * 256 + tid, r, o);
    bSrc[i] = Bt + (size_t)(n0 + r) * Ksz + o * 8;
  }

  auto stage = [&](int buf) {
#pragma unroll
    for (int half = 0; half < 2; half++) {
#pragma unroll
      for (int i = 0; i < CA; i++)
        gld16(aSrc[i] + half * 32, (char*)sm + buf * ABy + half * (BM * 64) + i * 4096 + w * 1024);
#pragma unroll
      for (int i = 0; i < 2; i++)
        gld16(bSrc[i] + half * 32, (char*)sm + Bbase + buf * 16384 + half * 8192 + i * 4096 + w * 1024);
    }
#pragma unroll
    for (int i = 0; i < CA; i++) aSrc[i] += 64;
#pragma unroll
    for (int i = 0; i < 2; i++) bSrc[i] += 64;
  };

  f32x4 acc[MT][4] = {};
  const int NK = Ksz / 64;
  stage(0);
  for (int j = 0; j < NK; j++) {
    const int cur = j & 1;
    if (j + 1 < NK) {
      stage(cur ^ 1);
      if constexpr (CA == 2) asm volatile("s_waitcnt vmcnt(8)" ::: "memory");
      else                   asm volatile("s_waitcnt vmcnt(6)" ::: "memory");
    } else {
      asm volatile("s_waitcnt vmcnt(0)" ::: "memory");
    }
    __builtin_amdgcn_s_barrier();
    asm volatile("" ::: "memory");

#pragma unroll
    for (int kk = 0; kk < 2; kk++) {
      bf16x8 aF[MT], bF[4];
#pragma unroll
      for (int m = 0; m < MT; m++) {
        int row = wm * (BM / 2) + m * 16 + cl;
        unsigned ba = (unsigned)((row * 64 + rg * 16) ^ ((row & 7) << 4));
        aF[m] = *(const bf16x8*)((char*)sm + cur * ABy + kk * (BM * 64) + ba);
      }
#pragma unroll
      for (int n = 0; n < 4; n++) {
        int row = wn * 64 + n * 16 + cl;
        unsigned ba = (unsigned)((row * 64 + rg * 16) ^ ((row & 7) << 4));
        bF[n] = *(const bf16x8*)((char*)sm + Bbase + cur * 16384 + kk * 8192 + ba);
      }
      __builtin_amdgcn_s_setprio(1);
#pragma unroll
      for (int m = 0; m < MT; m++)
#pragma unroll
        for (int n = 0; n < 4; n++)
          acc[m][n] = __builtin_amdgcn_mfma_f32_16x16x32_bf16(aF[m], bF[n], acc[m][n], 0, 0, 0);
      __builtin_amdgcn_s_setprio(0);
    }
    asm volatile("" ::: "memory");
    __builtin_amdgcn_s_barrier();
  }

  if constexpr (EPI == 0) {
#pragma unroll
    for (int m = 0; m < MT; m++)
#pragma unroll
      for (int n = 0; n < 4; n++)
#pragma unroll
        for (int r = 0; r < 4; r++)
          C[(size_t)(m0 + wm * (BM / 2) + m * 16 + rg * 4 + r) * Nsz + n0 + wn * 64 + n * 16 + cl] =
              acc[m][n][r];
  } else {
    const int col0 = n0 + wn * 64;   // 64-aligned -> exactly one head; branch block-uniform
    if (col0 < 1536) {
      const bool isQ = col0 < 1024;
      const float scale = isQ ? 0.125f : 1.0f;
      u16* dst = isQ ? Qb : Kb;
      const int hh = isQ ? (col0 >> 6) : ((col0 - 1024) >> 6);
      const int HN = isQ ? 16 : 8;
#pragma unroll
      for (int m = 0; m < MT; m++)
#pragma unroll
        for (int r = 0; r < 4; r++) {
          int tg = m0 + wm * (BM / 2) + m * 16 + rg * 4 + r;
          int bb = tg >> 11, tt = tg & 2047;
          size_t base = ((size_t)(bb * HN + hh) * 2048 + tt) * 64;
#pragma unroll
          for (int n = 0; n < 4; n++) {
            int d = n * 16 + cl;
            float cv = cs[tt * 64 + d], sv = sn[tt * 64 + d];
            float partner = acc[m][n ^ 2][r];
            float val = acc[m][n][r] * cv + ((n < 2) ? -partner : partner) * sv;
            dst[base + d] = f2b(val * scale);
          }
        }
    } else {
      // ---- fused V transpose: acc tile (128t x 128d) -> LDS [t][130] -> Vt[d][t] coalesced ----
      __syncthreads();
      u16* tb = sm;
#pragma unroll
      for (int m = 0; m < MT; m++)
#pragma unroll
        for (int r = 0; r < 4; r++) {
          int tr = wm * (BM / 2) + m * 16 + rg * 4 + r;
#pragma unroll
          for (int n = 0; n < 4; n++)
            tb[tr * 130 + wn * 64 + n * 16 + cl] = f2b(acc[m][n][r]);
        }
      __syncthreads();
      const int bb = m0 >> 11, t0 = m0 & 2047;
#pragma unroll
      for (int i = 0; i < 32; i++) {
        int idx = i * 256 + tid;
        int d = idx >> 6, tp = (idx & 63) * 2;
        u32 v = (u32)tb[tp * 130 + d] | ((u32)tb[(tp + 1) * 130 + d] << 16);
        int dcol = n0 - 1536 + d;
        *(u32*)(Vt + (((size_t)(bb * 8) + (dcol >> 6)) * 64 + (dcol & 63)) * 2048 + t0 + tp) = v;
      }
    }
  }
}

// ---- causal flash attention v20: r16 grid/structure + ring-of-3 staging, counted vmcnt(4) ----
// Per step: {vmcnt(4|0) -> barrier -> STAGE(i+2) -> compute(i)}. Tile-i loads get TWO compute
// phases of latency budget. Race-free: buf (i+2)%3's readers finished compute(i-1) before
// barrier@i; each wave's own vmcnt before the barrier guarantees tile-i visibility after it.
__global__ __launch_bounds__(256, 4) void k_flash20(const u16* __restrict__ Qb, const u16* __restrict__ Kb,
                                                    const u16* __restrict__ Vt, u16* __restrict__ Ob) {
  __shared__ u16 smem[24576];  // 48KB: 2 streams x [K ring 3x4KB | V ring 3x4KB]
  const int tid = threadIdx.x;
  const int l = tid & 63, w = tid >> 6;
  const int sid = w >> 1;        // kv stream 0..1
  const int h01 = w & 1;         // head within kh
  const int bid = blockIdx.x;
  const int bkh = bid & 15;
  const int j = bid >> 4, quad = j >> 4, jj = j & 15;
  const int qt = (quad == 0) ? 63 - jj : (quad == 1) ? jj : (quad == 2) ? 47 - jj : 16 + jj;
  const int b = bkh >> 3, kh = bkh & 7;
  const int h = kh * 2 + h01;
  const int q0 = qt * 32;
  const int lq = l & 31, hi = l >> 5;
  const int q = q0 + lq;

  const int cnt = (qt + 2 - sid) >> 1;   // tiles for this stream (t = sid + 2i)
  const int CNTMAX = (qt + 2) >> 1;

  const u16* Kg = Kb + (size_t)(b * 8 + kh) * 2048 * 64;
  const u16* Vg = Vt + (size_t)(b * 8 + kh) * 64 * 2048;
  const u16* Qp = Qb + ((size_t)(b * 16 + h) * 2048 + q) * 64 + hi * 8;

  const int krow = h01 * 16 + (l >> 3);
  const int swk1 = (krow ^ (krow >> 3)) & 7;
  const int swk2 = ((krow + 8) ^ ((krow + 8) >> 3)) & 7;
  const u16* kS1 = Kg + (size_t)(sid * 32 + krow) * 64 + (((l & 7) ^ swk1) << 3);
  const u16* kS2 = Kg + (size_t)(sid * 32 + krow + 8) * 64 + (((l & 7) ^ swk2) << 3);
  const int vd = h01 * 32 + (l >> 2);
  const int swv1 = ((vd >> 1) ^ (vd >> 3)) & 3;
  const int swv2 = (((vd + 16) >> 1) ^ ((vd + 16) >> 3)) & 3;
  const u16* vS0 = Vg + (size_t)vd * 2048 + sid * 32 + (((l & 3) ^ swv1) << 3);
  const u16* vS1 = Vg + (size_t)(vd + 16) * 2048 + sid * 32 + (((l & 3) ^ swv2) << 3);
  char* smB = (char*)smem;
  const int kDst = sid * 24576 + h01 * 2048;
  const int vDst = sid * 24576 + 12288 + h01 * 2048;

#define STAGE(buf)                                         \
  {                                                        \
    gld16(kS1, smB + kDst + (buf) * 4096);                 \
    gld16(kS2, smB + kDst + (buf) * 4096 + 1024);          \
    gld16(vS0, smB + vDst + (buf) * 4096);                 \
    gld16(vS1, smB + vDst + (buf) * 4096 + 1024);          \
    kS1 += 4096; kS2 += 4096; vS0 += 64; vS1 += 64;        \
  }

  if (cnt > 0) STAGE(0);
  if (cnt > 1) STAGE(1);

  bf16x8 qf[4];
#pragma unroll
  for (int ks = 0; ks < 4; ks++) qf[ks] = *(const bf16x8*)(Qp + ks * 16);

  union { u32 uu[4]; bf16x8 v; } ones;
#pragma unroll
  for (int jo = 0; jo < 4; jo++) ones.uu[jo] = 0x3F803F80u;

  f32x16 oa[2] = {};
  f32x16 lacc = {};
  float m = -3e38f;
  const int swzkr = (lq ^ (lq >> 3)) & 7;
  const int swzvr = ((lq >> 1) ^ (lq >> 3)) & 3;
  int cur = 0;

  for (int i = 0; i < CNTMAX; i++) {
    if (i + 1 < cnt) asm volatile("s_waitcnt vmcnt(4)" ::: "memory");
    else             asm volatile("s_waitcnt vmcnt(0)" ::: "memory");
    __builtin_amdgcn_s_barrier();
    asm volatile("" ::: "memory");
    if (i + 2 < cnt) STAGE(cur == 0 ? 2 : cur - 1);   // (cur+2)%3

    if (i < cnt) {
      const int t = sid + 2 * i;
      const char* KL = smB + sid * 24576 + cur * 4096;
      const char* VL = smB + sid * 24576 + 12288 + cur * 4096;

      bf16x8 kf[4];
#pragma unroll
      for (int ks = 0; ks < 4; ks++)
        kf[ks] = *(const bf16x8*)(KL + lq * 128 + ((((ks << 1) | hi) ^ swzkr) << 4));
      f32x16 s0 = {};
      __builtin_amdgcn_s_setprio(1);
#pragma unroll
      for (int ks = 0; ks < 4; ks++)
        s0 = __builtin_amdgcn_mfma_f32_32x32x16_bf16(kf[ks], qf[ks], s0, 0, 0, 0);
      __builtin_amdgcn_s_setprio(0);

      if (t == qt) {
#pragma unroll
        for (int r = 0; r < 16; r++) {
          int kvr = (t << 5) + (r & 3) + 8 * (r >> 2) + 4 * hi;
          if (kvr > q) s0[r] = -3e38f;
        }
      }

      float a5[5];
#pragma unroll
      for (int jo = 0; jo < 5; jo++) a5[jo] = max3f(s0[3 * jo], s0[3 * jo + 1], s0[3 * jo + 2]);
      float mx16 = fmaxf(max3f(a5[0], a5[1], a5[2]), max3f(a5[3], a5[4], s0[15]));
      bool keep = __all(mx16 - m <= 8.f);
      if (!keep) {
        float mx = fmaxf(mx16, __shfl_xor(mx16, 32, 64));
        float mnew = fmaxf(m, mx);
        float alpha = exp2f((m - mnew) * LOG2E);
        m = mnew;
        lacc[0] *= alpha;
#pragma unroll
        for (int r = 0; r < 16; r++) { oa[0][r] *= alpha; oa[1][r] *= alpha; }
      }
      float mb = m * LOG2E;
#pragma unroll
      for (int r = 0; r < 16; r++) s0[r] = exp2f(fmaf(s0[r], LOG2E, -mb));

      u32 aw[8];
#pragma unroll
      for (int jo = 0; jo < 8; jo++) aw[jo] = cvtpk(s0[2 * jo], s0[2 * jo + 1]);
      plswap(aw[0], aw[2]); plswap(aw[1], aw[3]);
      plswap(aw[4], aw[6]); plswap(aw[5], aw[7]);
      union { u32 uu[4]; bf16x8 v; } p0, p1;
#pragma unroll
      for (int jo = 0; jo < 4; jo++) { p0.uu[jo] = aw[jo]; p1.uu[jo] = aw[4 + jo]; }

      bf16x8 vf[2][2];
#pragma unroll
      for (int dt = 0; dt < 2; dt++)
#pragma unroll
        for (int p = 0; p < 2; p++)
          vf[dt][p] = *(const bf16x8*)(VL + (dt * 32 + lq) * 64 + ((((p << 1) | hi) ^ swzvr) << 4));

      __builtin_amdgcn_s_setprio(1);
#pragma unroll
      for (int dt = 0; dt < 2; dt++) {
        oa[dt] = __builtin_amdgcn_mfma_f32_32x32x16_bf16(vf[dt][0], p0.v, oa[dt], 0, 0, 0);
        oa[dt] = __builtin_amdgcn_mfma_f32_32x32x16_bf16(vf[dt][1], p1.v, oa[dt], 0, 0, 0);
      }
      lacc = __builtin_amdgcn_mfma_f32_32x32x16_bf16(ones.v, p0.v, lacc, 0, 0, 0);
      lacc = __builtin_amdgcn_mfma_f32_32x32x16_bf16(ones.v, p1.v, lacc, 0, 0, 0);
      __builtin_amdgcn_s_setprio(0);
    }
    cur = (cur == 2) ? 0 : cur + 1;
    asm volatile("" ::: "memory");
  }

  float lsum = lacc[0];

  // ---- 2-way merge per head (overlay staging LDS) ----
  __syncthreads();
  float* pbuf = (float*)smem;                       // [2][64][33] f32
  float* mlb = (float*)((char*)smem + 16896);       // [2][128] f32
  u32* otileB = (u32*)((char*)smem + 17920);        // [2][32*33] u32
  if (sid == 1) {
    float* pb = pbuf + (h01 * 64 + l) * 33;
#pragma unroll
    for (int r = 0; r < 16; r++) { pb[r] = oa[0][r]; pb[16 + r] = oa[1][r]; }
    mlb[h01 * 128 + l] = m;
    mlb[h01 * 128 + 64 + l] = lsum;
  }
  __syncthreads();
  if (sid == 0) {
    float m1 = mlb[h01 * 128 + l], l1 = mlb[h01 * 128 + 64 + l];
    float ms = fmaxf(m, m1);
    float a0 = exp2f((m - ms) * LOG2E);
    float a1 = exp2f((m1 - ms) * LOG2E);
    float linv = 1.0f / (lsum * a0 + l1 * a1);
    a0 *= linv; a1 *= linv;
    const float* pb = pbuf + (h01 * 64 + l) * 33;
    float of[32];
#pragma unroll
    for (int r = 0; r < 16; r++) {
      of[r] = oa[0][r] * a0 + pb[r] * a1;
      of[16 + r] = oa[1][r] * a0 + pb[16 + r] * a1;
    }
    u32* ot = otileB + h01 * (32 * 33);
#pragma unroll
    for (int dt = 0; dt < 2; dt++)
#pragma unroll
      for (int r = 0; r < 16; r += 2) {
        int d = dt * 32 + (r & 3) + 8 * (r >> 2) + 4 * hi;
        ot[lq * 33 + (d >> 1)] = cvtpk(of[dt * 16 + r], of[dt * 16 + r + 1]);
      }
#pragma unroll
    for (int i2 = 0; i2 < 16; i2++) {
      int wd = i2 * 64 + l;
      int row = wd >> 5, col = wd & 31;
      u32 v = ot[row * 33 + col];
      *(u32*)(Ob + (size_t)(b * 2048 + q0 + row) * 1024 + h * 64 + col * 2) = v;
    }
  }
#undef STAGE
}

extern "C" void kernel_launch(void* const* d_in, const int* in_sizes, int n_in,
                              void* d_out, int out_size, void* d_ws, size_t ws_size,
                              hipStream_t stream) {
  const float* x = (const float*)d_in[0];
  const float* cs = (const float*)d_in[1];
  const float* sn = (const float*)d_in[2];
  const float* w_qkv = (const float*)d_in[3];
  const float* w_out = (const float*)d_in[4];
  float* out = (float*)d_out;
  char* ws = (char*)d_ws;

  u16* Xb  = (u16*)(ws);                       // 8 MB  [4096][1024]
  u16* Wqt = (u16*)(ws + ((size_t)8u << 20));  // 4 MB  [2048][1024]
  u16* Wot = (u16*)(ws + ((size_t)12u << 20)); // 2 MB  [1024][1024]
  u16* Qb  = (u16*)(ws + ((size_t)18u << 20)); // 8 MB  [2][16][2048][64]
  u16* Kb  = (u16*)(ws + ((size_t)26u << 20)); // 4 MB  [2][8][2048][64]
  u16* Vt  = (u16*)(ws + ((size_t)30u << 20)); // 4 MB  [2][8][64][2048]
  u16* Ob  = (u16*)(ws + ((size_t)34u << 20)); // 8 MB  [4096][1024]

  k_prep0<<<7168, 256, 0, stream>>>(x, Xb, w_qkv, Wqt, w_out, Wot);
  k_gemm<128, 2048, 1024, 1><<<dim3(32, 16), 256, 0, stream>>>(Xb, Wqt, nullptr, cs, sn, Qb, Kb, Vt);
  k_flash20<<<1024, 256, 0, stream>>>(Qb, Kb, Vt, Ob);
  k_gemm<64, 1024, 1024, 0><<<dim3(64, 8), 256, 0, stream>>>(Ob, Wot, out, nullptr, nullptr, nullptr, nullptr, nullptr);
}

// Round 21
// 88.837 us; speedup vs baseline: 1.2043x; 1.2043x over previous
//
#include <hip/hip_runtime.h>

typedef unsigned short u16;
typedef unsigned int u32;
typedef short bf16x8 __attribute__((ext_vector_type(8)));
typedef float f32x4 __attribute__((ext_vector_type(4)));
typedef float f32x8v __attribute__((ext_vector_type(8)));
typedef float f32x16 __attribute__((ext_vector_type(16)));

#define LOG2E 1.44269504f

__device__ __forceinline__ u16 f2b(float f) {
  union { float f; unsigned u; } v; v.f = f;
  unsigned r = v.u + 0x7FFFu + ((v.u >> 16) & 1u);
  return (u16)(r >> 16);
}

__device__ __forceinline__ u32 cvtpk(float a, float b) {
  u32 r;
  asm("v_cvt_pk_bf16_f32 %0, %1, %2" : "=v"(r) : "v"(a), "v"(b));
  return r;
}

__device__ __forceinline__ float max3f(float a, float b, float c) {
  float r;
  asm("v_max3_f32 %0, %1, %2, %3" : "=v"(r) : "v"(a), "v"(b), "v"(c));
  return r;
}

__device__ __forceinline__ void plswap(u32& x, u32& y) {
#if __has_builtin(__builtin_amdgcn_permlane32_swap)
  typedef int v2i __attribute__((ext_vector_type(2)));
  v2i r = __builtin_amdgcn_permlane32_swap((int)x, (int)y, false, false);
  x = (u32)r[0]; y = (u32)r[1];
#else
  u32 sx = (u32)__shfl_xor((int)x, 32, 64);
  u32 sy = (u32)__shfl_xor((int)y, 32, 64);
  bool hi = (threadIdx.x & 63) >= 32;
  u32 nx = hi ? sy : x;
  u32 ny = hi ? y : sx;
  x = nx; y = ny;
#endif
}

// async global->LDS, 16B per lane; LDS dest is wave-uniform base (HW adds lane*16)
__device__ __forceinline__ void gld16(const void* g, void* l) {
  __builtin_amdgcn_global_load_lds((const __attribute__((address_space(1))) void*)g,
                                   (__attribute__((address_space(3))) void*)l, 16, 0, 0);
}

// inverse of LDS fragment swizzle ba(r,o) = (r*64 + o*16) ^ ((r&7)<<4), L = c*16
__device__ __forceinline__ void invswz(int c, int& r, int& o) {
  int rhalf = c >> 3;
  int r2 = (rhalf >> 1) & 1;
  int r0 = ((c >> 2) & 1) ^ r2;
  r = rhalf * 2 + r0;
  int o0 = (c & 1) ^ r0;
  int o1 = ((c >> 1) & 1) ^ (rhalf & 1);
  o = o0 + 2 * o1;
}

// ------------- prep0: cast x (blk<4096) | transpose w_qkv (<6144) | transpose w_out -------------
__global__ __launch_bounds__(256) void k_prep0(const float* __restrict__ x, u16* __restrict__ Xb,
                                               const float* __restrict__ w_qkv, u16* __restrict__ Wqt,
                                               const float* __restrict__ w_out, u16* __restrict__ Wot) {
  __shared__ float tile[32][33];
  int blk = blockIdx.x;
  int tid = threadIdx.x;
  if (blk < 4096) {
    int i = blk * 256 + tid;
    float4 v = ((const float4*)x)[i];
    ushort4 o;
    o.x = f2b(v.x); o.y = f2b(v.y); o.z = f2b(v.z); o.w = f2b(v.w);
    ((ushort4*)Xb)[i] = o;
    return;
  }
  const float* in; u16* out; int R, C, t;
  if (blk < 6144) { t = blk - 4096; in = w_qkv; out = Wqt; R = 1024; C = 2048; }
  else            { t = blk - 6144; in = w_out; out = Wot; R = 1024; C = 1024; }
  int nbx = C >> 5;
  int c0 = (t % nbx) * 32, r0 = (t / nbx) * 32;
  int tx = tid & 31, ty = tid >> 5;
#pragma unroll
  for (int i = 0; i < 32; i += 8)
    tile[ty + i][tx] = in[(size_t)(r0 + ty + i) * C + c0 + tx];
  __syncthreads();
#pragma unroll
  for (int i = 0; i < 32; i += 8)
    out[(size_t)(c0 + ty + i) * R + r0 + tx] = f2b(tile[tx][ty + i]);
}

// ------------- GEMM: BMx128 tile, BK=64 per barrier step (2 swizzled BK=32 halves),
// global_load_lds staging (pre-swizzled source), dbuf, counted vmcnt.
// EPI 0: C fp32 store. EPI 1 (qkv): cols<1536 -> in-register RoPE -> Qb/Kb bf16;
//                                   cols>=1536 -> LDS transpose -> Vt[b*8+kh][d][t] bf16.
template<int BM, int Nsz, int Ksz, int EPI>
__global__ __launch_bounds__(256) void k_gemm(const u16* __restrict__ A, const u16* __restrict__ Bt,
                                              float* __restrict__ C, const float* __restrict__ cs,
                                              const float* __restrict__ sn, u16* __restrict__ Qb,
                                              u16* __restrict__ Kb, u16* __restrict__ Vt) {
  constexpr int MT = BM / 32;       // acc m-tiles per wave
  constexpr int CA = BM / 64;       // A staging calls per K-half
  constexpr int ABy = BM * 128;     // A bytes per buf (BK=64)
  __shared__ u16 sm[BM * 128 + 16384];  // A 2buf + B 2buf; EPI1 epilogue reuse needs 16640 < 32768
  const int tid = threadIdx.x;
  const int l = tid & 63, w = tid >> 6;
  const int wm = w >> 1, wn = w & 1;
  const int m0 = blockIdx.x * BM, n0 = blockIdx.y * 128;
  const int rg = l >> 4, cl = l & 15;
  const int Bbase = BM * 256;       // byte offset of B region

  // staging sources: lane's linear LDS slot c -> (row,off) via inverse swizzle (per K-half)
  const u16* aSrc[2];
  const u16* bSrc[2];
#pragma unroll
  for (int i = 0; i < CA; i++) {
    int r, o; invswz(i * 256 + tid, r, o);
    aSrc[i] = A + (size_t)(m0 + r) * Ksz + o * 8;
  }
#pragma unroll
  for (int i = 0; i < 2; i++) {
    int r, o; invswz(i * 256 + tid, r, o);
    bSrc[i] = Bt + (size_t)(n0 + r) * Ksz + o * 8;
  }

  auto stage = [&](int buf) {
#pragma unroll
    for (int half = 0; half < 2; half++) {
#pragma unroll
      for (int i = 0; i < CA; i++)
        gld16(aSrc[i] + half * 32, (char*)sm + buf * ABy + half * (BM * 64) + i * 4096 + w * 1024);
#pragma unroll
      for (int i = 0; i < 2; i++)
        gld16(bSrc[i] + half * 32, (char*)sm + Bbase + buf * 16384 + half * 8192 + i * 4096 + w * 1024);
    }
#pragma unroll
    for (int i = 0; i < CA; i++) aSrc[i] += 64;
#pragma unroll
    for (int i = 0; i < 2; i++) bSrc[i] += 64;
  };

  f32x4 acc[MT][4] = {};
  const int NK = Ksz / 64;
  stage(0);
  for (int j = 0; j < NK; j++) {
    const int cur = j & 1;
    if (j + 1 < NK) {
      stage(cur ^ 1);
      if constexpr (CA == 2) asm volatile("s_waitcnt vmcnt(8)" ::: "memory");
      else                   asm volatile("s_waitcnt vmcnt(6)" ::: "memory");
    } else {
      asm volatile("s_waitcnt vmcnt(0)" ::: "memory");
    }
    __builtin_amdgcn_s_barrier();
    asm volatile("" ::: "memory");

#pragma unroll
    for (int kk = 0; kk < 2; kk++) {
      bf16x8 aF[MT], bF[4];
#pragma unroll
      for (int m = 0; m < MT; m++) {
        int row = wm * (BM / 2) + m * 16 + cl;
        unsigned ba = (unsigned)((row * 64 + rg * 16) ^ ((row & 7) << 4));
        aF[m] = *(const bf16x8*)((char*)sm + cur * ABy + kk * (BM * 64) + ba);
      }
#pragma unroll
      for (int n = 0; n < 4; n++) {
        int row = wn * 64 + n * 16 + cl;
        unsigned ba = (unsigned)((row * 64 + rg * 16) ^ ((row & 7) << 4));
        bF[n] = *(const bf16x8*)((char*)sm + Bbase + cur * 16384 + kk * 8192 + ba);
      }
      __builtin_amdgcn_s_setprio(1);
#pragma unroll
      for (int m = 0; m < MT; m++)
#pragma unroll
        for (int n = 0; n < 4; n++)
          acc[m][n] = __builtin_amdgcn_mfma_f32_16x16x32_bf16(aF[m], bF[n], acc[m][n], 0, 0, 0);
      __builtin_amdgcn_s_setprio(0);
    }
    asm volatile("" ::: "memory");
    __builtin_amdgcn_s_barrier();
  }

  if constexpr (EPI == 0) {
#pragma unroll
    for (int m = 0; m < MT; m++)
#pragma unroll
      for (int n = 0; n < 4; n++)
#pragma unroll
        for (int r = 0; r < 4; r++)
          C[(size_t)(m0 + wm * (BM / 2) + m * 16 + rg * 4 + r) * Nsz + n0 + wn * 64 + n * 16 + cl] =
              acc[m][n][r];
  } else {
    const int col0 = n0 + wn * 64;   // 64-aligned -> exactly one head; branch block-uniform
    if (col0 < 1536) {
      const bool isQ = col0 < 1024;
      const float scale = isQ ? 0.125f : 1.0f;
      u16* dst = isQ ? Qb : Kb;
      const int hh = isQ ? (col0 >> 6) : ((col0 - 1024) >> 6);
      const int HN = isQ ? 16 : 8;
#pragma unroll
      for (int m = 0; m < MT; m++)
#pragma unroll
        for (int r = 0; r < 4; r++) {
          int tg = m0 + wm * (BM / 2) + m * 16 + rg * 4 + r;
          int bb = tg >> 11, tt = tg & 2047;
          size_t base = ((size_t)(bb * HN + hh) * 2048 + tt) * 64;
#pragma unroll
          for (int n = 0; n < 4; n++) {
            int d = n * 16 + cl;
            float cv = cs[tt * 64 + d], sv = sn[tt * 64 + d];
            float partner = acc[m][n ^ 2][r];
            float val = acc[m][n][r] * cv + ((n < 2) ? -partner : partner) * sv;
            dst[base + d] = f2b(val * scale);
          }
        }
    } else {
      // ---- fused V transpose: acc tile (128t x 128d) -> LDS [t][130] -> Vt[d][t] coalesced ----
      __syncthreads();
      u16* tb = sm;
#pragma unroll
      for (int m = 0; m < MT; m++)
#pragma unroll
        for (int r = 0; r < 4; r++) {
          int tr = wm * (BM / 2) + m * 16 + rg * 4 + r;
#pragma unroll
          for (int n = 0; n < 4; n++)
            tb[tr * 130 + wn * 64 + n * 16 + cl] = f2b(acc[m][n][r]);
        }
      __syncthreads();
      const int bb = m0 >> 11, t0 = m0 & 2047;
#pragma unroll
      for (int i = 0; i < 32; i++) {
        int idx = i * 256 + tid;
        int d = idx >> 6, tp = (idx & 63) * 2;
        u32 v = (u32)tb[tp * 130 + d] | ((u32)tb[(tp + 1) * 130 + d] << 16);
        int dcol = n0 - 1536 + d;
        *(u32*)(Vt + (((size_t)(bb * 8) + (dcol >> 6)) * 64 + (dcol & 63)) * 2048 + t0 + tp) = v;
      }
    }
  }
}

// ---- causal flash attention v16 (verbatim r16): quadrant qt map, dbuf-2, one barrier/tile ----
__global__ __launch_bounds__(256, 4) void k_flash16(const u16* __restrict__ Qb, const u16* __restrict__ Kb,
                                                    const u16* __restrict__ Vt, u16* __restrict__ Ob) {
  __shared__ u16 smem[16384];  // 32KB: 2 streams x [K dbuf 2x4KB | V dbuf 2x4KB]
  const int tid = threadIdx.x;
  const int l = tid & 63, w = tid >> 6;
  const int sid = w >> 1;        // kv stream 0..1
  const int h01 = w & 1;         // head within kh
  const int bid = blockIdx.x;
  const int bkh = bid & 15;
  const int j = bid >> 4, quad = j >> 4, jj = j & 15;
  const int qt = (quad == 0) ? 63 - jj : (quad == 1) ? jj : (quad == 2) ? 47 - jj : 16 + jj;
  const int b = bkh >> 3, kh = bkh & 7;
  const int h = kh * 2 + h01;
  const int q0 = qt * 32;
  const int lq = l & 31, hi = l >> 5;
  const int q = q0 + lq;

  const int cnt = (qt + 2 - sid) >> 1;   // tiles for this stream (t = sid + 2i)
  const int CNTMAX = (qt + 2) >> 1;

  const u16* Kg = Kb + (size_t)(b * 8 + kh) * 2048 * 64;
  const u16* Vg = Vt + (size_t)(b * 8 + kh) * 64 * 2048;
  const u16* Qp = Qb + ((size_t)(b * 16 + h) * 2048 + q) * 64 + hi * 8;

  const int krow = h01 * 16 + (l >> 3);
  const int swk1 = (krow ^ (krow >> 3)) & 7;
  const int swk2 = ((krow + 8) ^ ((krow + 8) >> 3)) & 7;
  const u16* kS1 = Kg + (size_t)(sid * 32 + krow) * 64 + (((l & 7) ^ swk1) << 3);
  const u16* kS2 = Kg + (size_t)(sid * 32 + krow + 8) * 64 + (((l & 7) ^ swk2) << 3);
  const int vd = h01 * 32 + (l >> 2);
  const int swv1 = ((vd >> 1) ^ (vd >> 3)) & 3;
  const int swv2 = (((vd + 16) >> 1) ^ ((vd + 16) >> 3)) & 3;
  const u16* vS0 = Vg + (size_t)vd * 2048 + sid * 32 + (((l & 3) ^ swv1) << 3);
  const u16* vS1 = Vg + (size_t)(vd + 16) * 2048 + sid * 32 + (((l & 3) ^ swv2) << 3);
  char* smB = (char*)smem;
  const int kDst = sid * 16384 + h01 * 2048;
  const int vDst = sid * 16384 + 8192 + h01 * 2048;

#define STAGE(buf)                                         \
  {                                                        \
    gld16(kS1, smB + kDst + (buf) * 4096);                 \
    gld16(kS2, smB + kDst + (buf) * 4096 + 1024);          \
    gld16(vS0, smB + vDst + (buf) * 4096);                 \
    gld16(vS1, smB + vDst + (buf) * 4096 + 1024);          \
    kS1 += 4096; kS2 += 4096; vS0 += 64; vS1 += 64;        \
  }

  if (cnt > 0) STAGE(0);

  bf16x8 qf[4];
#pragma unroll
  for (int ks = 0; ks < 4; ks++) qf[ks] = *(const bf16x8*)(Qp + ks * 16);

  union { u32 uu[4]; bf16x8 v; } ones;
#pragma unroll
  for (int jo = 0; jo < 4; jo++) ones.uu[jo] = 0x3F803F80u;

  f32x16 oa[2] = {};
  f32x16 lacc = {};
  float m = -3e38f;
  const int swzkr = (lq ^ (lq >> 3)) & 7;
  const int swzvr = ((lq >> 1) ^ (lq >> 3)) & 3;

  for (int i = 0; i < CNTMAX; i++) {
    const int cur = i & 1;
    asm volatile("s_waitcnt vmcnt(0)" ::: "memory");
    __builtin_amdgcn_s_barrier();
    asm volatile("" ::: "memory");
    if (i + 1 < cnt) STAGE(cur ^ 1);

    if (i < cnt) {
      const int t = sid + 2 * i;
      const char* KL = smB + sid * 16384 + cur * 4096;
      const char* VL = smB + sid * 16384 + 8192 + cur * 4096;

      bf16x8 kf[4];
#pragma unroll
      for (int ks = 0; ks < 4; ks++)
        kf[ks] = *(const bf16x8*)(KL + lq * 128 + ((((ks << 1) | hi) ^ swzkr) << 4));
      f32x16 s0 = {};
      __builtin_amdgcn_s_setprio(1);
#pragma unroll
      for (int ks = 0; ks < 4; ks++)
        s0 = __builtin_amdgcn_mfma_f32_32x32x16_bf16(kf[ks], qf[ks], s0, 0, 0, 0);
      __builtin_amdgcn_s_setprio(0);

      if (t == qt) {
#pragma unroll
        for (int r = 0; r < 16; r++) {
          int kvr = (t << 5) + (r & 3) + 8 * (r >> 2) + 4 * hi;
          if (kvr > q) s0[r] = -3e38f;
        }
      }

      float a5[5];
#pragma unroll
      for (int jo = 0; jo < 5; jo++) a5[jo] = max3f(s0[3 * jo], s0[3 * jo + 1], s0[3 * jo + 2]);
      float mx16 = fmaxf(max3f(a5[0], a5[1], a5[2]), max3f(a5[3], a5[4], s0[15]));
      bool keep = __all(mx16 - m <= 8.f);
      if (!keep) {
        float mx = fmaxf(mx16, __shfl_xor(mx16, 32, 64));
        float mnew = fmaxf(m, mx);
        float alpha = exp2f((m - mnew) * LOG2E);
        m = mnew;
        lacc[0] *= alpha;
#pragma unroll
        for (int r = 0; r < 16; r++) { oa[0][r] *= alpha; oa[1][r] *= alpha; }
      }
      float mb = m * LOG2E;
#pragma unroll
      for (int r = 0; r < 16; r++) s0[r] = exp2f(fmaf(s0[r], LOG2E, -mb));

      u32 aw[8];
#pragma unroll
      for (int jo = 0; jo < 8; jo++) aw[jo] = cvtpk(s0[2 * jo], s0[2 * jo + 1]);
      plswap(aw[0], aw[2]); plswap(aw[1], aw[3]);
      plswap(aw[4], aw[6]); plswap(aw[5], aw[7]);
      union { u32 uu[4]; bf16x8 v; } p0, p1;
#pragma unroll
      for (int jo = 0; jo < 4; jo++) { p0.uu[jo] = aw[jo]; p1.uu[jo] = aw[4 + jo]; }

      bf16x8 vf[2][2];
#pragma unroll
      for (int dt = 0; dt < 2; dt++)
#pragma unroll
        for (int p = 0; p < 2; p++)
          vf[dt][p] = *(const bf16x8*)(VL + (dt * 32 + lq) * 64 + ((((p << 1) | hi) ^ swzvr) << 4));

      __builtin_amdgcn_s_setprio(1);
#pragma unroll
      for (int dt = 0; dt < 2; dt++) {
        oa[dt] = __builtin_amdgcn_mfma_f32_32x32x16_bf16(vf[dt][0], p0.v, oa[dt], 0, 0, 0);
        oa[dt] = __builtin_amdgcn_mfma_f32_32x32x16_bf16(vf[dt][1], p1.v, oa[dt], 0, 0, 0);
      }
      lacc = __builtin_amdgcn_mfma_f32_32x32x16_bf16(ones.v, p0.v, lacc, 0, 0, 0);
      lacc = __builtin_amdgcn_mfma_f32_32x32x16_bf16(ones.v, p1.v, lacc, 0, 0, 0);
      __builtin_amdgcn_s_setprio(0);
    }
    asm volatile("" ::: "memory");
  }

  float lsum = lacc[0];

  __syncthreads();
  float* pbuf = (float*)smem;                       // [2][64][33] f32
  float* mlb = (float*)((char*)smem + 16896);       // [2][128] f32
  u32* otileB = (u32*)((char*)smem + 17920);        // [2][32*33] u32
  if (sid == 1) {
    float* pb = pbuf + (h01 * 64 + l) * 33;
#pragma unroll
    for (int r = 0; r < 16; r++) { pb[r] = oa[0][r]; pb[16 + r] = oa[1][r]; }
    mlb[h01 * 128 + l] = m;
    mlb[h01 * 128 + 64 + l] = lsum;
  }
  __syncthreads();
  if (sid == 0) {
    float m1 = mlb[h01 * 128 + l], l1 = mlb[h01 * 128 + 64 + l];
    float ms = fmaxf(m, m1);
    float a0 = exp2f((m - ms) * LOG2E);
    float a1 = exp2f((m1 - ms) * LOG2E);
    float linv = 1.0f / (lsum * a0 + l1 * a1);
    a0 *= linv; a1 *= linv;
    const float* pb = pbuf + (h01 * 64 + l) * 33;
    float of[32];
#pragma unroll
    for (int r = 0; r < 16; r++) {
      of[r] = oa[0][r] * a0 + pb[r] * a1;
      of[16 + r] = oa[1][r] * a0 + pb[16 + r] * a1;
    }
    u32* ot = otileB + h01 * (32 * 33);
#pragma unroll
    for (int dt = 0; dt < 2; dt++)
#pragma unroll
      for (int r = 0; r < 16; r += 2) {
        int d = dt * 32 + (r & 3) + 8 * (r >> 2) + 4 * hi;
        ot[lq * 33 + (d >> 1)] = cvtpk(of[dt * 16 + r], of[dt * 16 + r + 1]);
      }
#pragma unroll
    for (int i2 = 0; i2 < 16; i2++) {
      int wd = i2 * 64 + l;
      int row = wd >> 5, col = wd & 31;
      u32 v = ot[row * 33 + col];
      *(u32*)(Ob + (size_t)(b * 2048 + q0 + row) * 1024 + h * 64 + col * 2) = v;
    }
  }
#undef STAGE
}

extern "C" void kernel_launch(void* const* d_in, const int* in_sizes, int n_in,
                              void* d_out, int out_size, void* d_ws, size_t ws_size,
                              hipStream_t stream) {
  const float* x = (const float*)d_in[0];
  const float* cs = (const float*)d_in[1];
  const float* sn = (const float*)d_in[2];
  const float* w_qkv = (const float*)d_in[3];
  const float* w_out = (const float*)d_in[4];
  float* out = (float*)d_out;
  char* ws = (char*)d_ws;

  u16* Xb  = (u16*)(ws);                       // 8 MB  [4096][1024]
  u16* Wqt = (u16*)(ws + ((size_t)8u << 20));  // 4 MB  [2048][1024]
  u16* Wot = (u16*)(ws + ((size_t)12u << 20)); // 2 MB  [1024][1024]
  u16* Qb  = (u16*)(ws + ((size_t)18u << 20)); // 8 MB  [2][16][2048][64]
  u16* Kb  = (u16*)(ws + ((size_t)26u << 20)); // 4 MB  [2][8][2048][64]
  u16* Vt  = (u16*)(ws + ((size_t)30u << 20)); // 4 MB  [2][8][64][2048]
  u16* Ob  = (u16*)(ws + ((size_t)34u << 20)); // 8 MB  [4096][1024]

  k_prep0<<<7168, 256, 0, stream>>>(x, Xb, w_qkv, Wqt, w_out, Wot);
  k_gemm<128, 2048, 1024, 1><<<dim3(32, 16), 256, 0, stream>>>(Xb, Wqt, nullptr, cs, sn, Qb, Kb, Vt);
  k_flash16<<<1024, 256, 0, stream>>>(Qb, Kb, Vt, Ob);
  k_gemm<64, 1024, 1024, 0><<<dim3(64, 8), 256, 0, stream>>>(Ob, Wot, out, nullptr, nullptr, nullptr, nullptr, nullptr);
}